// Round 3
// baseline (8544.743 us; speedup 1.0000x reference)
//
#include <hip/hip_runtime.h>

typedef short short8 __attribute__((ext_vector_type(8)));
typedef float f32x4 __attribute__((ext_vector_type(4)));
typedef unsigned short u16;
typedef unsigned int u32;

#define C64 64
#define H512 512
#define W512 512
#define HWp (H512*W512)
#define NWG 64
#define PR 72   // padded LDS row stride in u16 (144 B, 16B-aligned)

struct Ws {
  int flagTop[NWG][2];       // 256 ints total (flags region)
  int flagBot[NWG][2];
  u32 haloTop[NWG][2][64];   // f32 bits, [band][parity][channel]
  u32 haloBot[NWG][2][64];
};
// lo-weight fragment arrays in d_ws after Ws
#define LOIH_OFF 66560
#define LOIH_ENT (3*4*6*64)          // (g,nblk,kk,lane) entries, 8 u16 each
#define LOHH_OFF (LOIH_OFF + LOIH_ENT*8*2)
#define LOHH_ENT (3*4*2*64)

__device__ __forceinline__ u16 f2bf(float f){
  u32 u = __float_as_uint(f);
  u += 0x7fffu + ((u >> 16) & 1u);
  return (u16)(u >> 16);
}
__device__ __forceinline__ float bf2f(u16 h){ return __uint_as_float(((u32)h) << 16); }
__device__ __forceinline__ f32x4 splat4(float x){ f32x4 v = {x,x,x,x}; return v; }
__device__ __forceinline__ float sigm(float x){ return 1.f/(1.f + __expf(-x)); }
__device__ __forceinline__ float tanh_(float x){ float e = __expf(2.f*x); return 1.f - 2.f/(e + 1.f); }

#define MFMA16(a,b,c) __builtin_amdgcn_mfma_f32_16x16x32_bf16(a,b,c,0,0,0)
#define ATOM_ST(p,v) __hip_atomic_store((p),(v),__ATOMIC_RELAXED,__HIP_MEMORY_SCOPE_AGENT)
#define ATOM_LD(p)   __hip_atomic_load((p),__ATOMIC_RELAXED,__HIP_MEMORY_SCOPE_AGENT)

// ---------- pre: reset sync flags (replay safety; kernel boundary = device fence) ----------
__global__ void reset_flags(int* flags) {
  flags[threadIdx.x] = -1;   // 256 flags exactly
}

// ---------- prep: build lo-weight fragments (w - bf16(w)) in fragment order ----------
__global__ void prep_lofrags(const float* __restrict__ w_ih,
                             const float* __restrict__ w_hh,
                             u16* __restrict__ loIH, u16* __restrict__ loHH) {
  int t = blockIdx.x * 256 + threadIdx.x;
  if (t < LOIH_ENT) {
    int lane = t & 63, e = t >> 6;
    int kk = e % 6; e /= 6; int nb = e % 4; int g = e / 4;
    int n = g*64 + nb*16 + (lane & 15);
    short8 v;
#pragma unroll
    for (int j = 0; j < 8; ++j) {
      float wv = w_ih[n*192 + kk*32 + (lane>>4)*8 + j];
      u16 h = f2bf(wv);
      v[j] = (short)f2bf(wv - bf2f(h));
    }
    *(short8*)&loIH[(size_t)t * 8] = v;
  } else if (t < LOIH_ENT + LOHH_ENT) {
    int u = t - LOIH_ENT;
    int lane = u & 63, e = u >> 6;
    int kt = e % 2; e /= 2; int nb = e % 4; int g = e / 4;
    int n = g*64 + nb*16 + (lane & 15);
    short8 v;
#pragma unroll
    for (int j = 0; j < 8; ++j) {
      float wv = w_hh[n*64 + kt*32 + (lane>>4)*8 + j];
      u16 h = f2bf(wv);
      v[j] = (short)f2bf(wv - bf2f(h));
    }
    *(short8*)&loHH[(size_t)u * 8] = v;
  }
}

// ---------- main scan ----------
__global__ __launch_bounds__(256, 1)
void gru_scan(const float* __restrict__ feat,
              const float* __restrict__ w_ih,
              const float* __restrict__ w_hh,
              const float* __restrict__ b_ih,
              const float* __restrict__ b_hh,
              float* __restrict__ out,
              Ws* __restrict__ ws,
              const u16* __restrict__ loIH,
              const u16* __restrict__ loHH)
{
  // state rows 0..33 = h0-1 .. h0+32 (prev output col), hi/lo bf16 planes
  __shared__ __align__(16) u16 sh[34*PR], sl[34*PR];
  __shared__ __align__(16) u16 uh[32*PR], ul[32*PR];
  __shared__ float s_curf[32*68];

  const int tid  = threadIdx.x;
  const int wg   = blockIdx.x;
  const int b    = wg >> 4;
  const int kband= wg & 15;
  const int h0   = kband * 32;
  const int lane = tid & 63;
  const int wid  = tid >> 6;   // 0..3
  const int rt   = wid >> 1;   // row-tile: rows rt*16..rt*16+15
  const int nh   = wid & 1;    // output-channel half
  const int ln16 = lane & 15;
  const int kgrp = lane >> 4;

  // ---- hi-weight fragments in registers ----
  short8 Bih[3][2][6];
  short8 Bhh[3][2][2];
  float biasR[2], biasZ[2], biasI[2], biasHn[2];
#pragma unroll
  for (int g = 0; g < 3; ++g)
#pragma unroll
    for (int p = 0; p < 2; ++p) {
      const int n = g*64 + nh*32 + p*16 + ln16;
#pragma unroll
      for (int kk = 0; kk < 6; ++kk) {
        short8 v;
#pragma unroll
        for (int j = 0; j < 8; ++j) v[j] = (short)f2bf(w_ih[n*192 + kk*32 + kgrp*8 + j]);
        Bih[g][p][kk] = v;
      }
#pragma unroll
      for (int kt = 0; kt < 2; ++kt) {
        short8 v;
#pragma unroll
        for (int j = 0; j < 8; ++j) v[j] = (short)f2bf(w_hh[n*64 + kt*32 + kgrp*8 + j]);
        Bhh[g][p][kt] = v;
      }
    }
#pragma unroll
  for (int p = 0; p < 2; ++p) {
    const int n0 = nh*32 + p*16 + ln16;
    biasR[p]  = b_ih[n0]       + b_hh[n0];
    biasZ[p]  = b_ih[64 + n0]  + b_hh[64 + n0];
    biasI[p]  = b_ih[128 + n0];
    biasHn[p] = b_hh[128 + n0];
  }

  // per-thread column-load mapping: 8 channels x 1 row
  const int hh = tid & 31;
  const int cb = (tid >> 5) * 8;
  const float* featT = feat + (size_t)(b*C64 + cb)*HWp + (size_t)(h0 + hh)*W512;
  float*       outT  = out  + (size_t)(b*C64 + cb)*HWp + (size_t)(h0 + hh)*W512;

  // ---- init: column 0 passes through and becomes the initial state ----
  {
    float cv[8];
#pragma unroll
    for (int j = 0; j < 8; ++j) cv[j] = featT[(size_t)j*HWp];
#pragma unroll
    for (int j = 0; j < 8; ++j) outT[(size_t)j*HWp] = cv[j];
#pragma unroll
    for (int j = 0; j < 8; ++j) {
      u16 h_ = f2bf(cv[j]);
      sh[(1+hh)*PR + cb + j] = h_;
      sl[(1+hh)*PR + cb + j] = f2bf(cv[j] - bf2f(h_));
    }
    if (tid < 64)       { sh[tid] = 0; sl[tid] = 0; }                       // row 0
    else if (tid < 128) { sh[33*PR + tid-64] = 0; sl[33*PR + tid-64] = 0; } // row 33
  }
  __syncthreads();

  // post step-0 halos (exact f32 = hi+lo), release-order via vmcnt(0), flag=0
  if (wid < 2) {
    if (lane < 32) {
      const int c = nh*32 + lane;
      float v = bf2f(sh[1*PR + c]) + bf2f(sl[1*PR + c]);
      ATOM_ST(&ws->haloTop[wg][0][c], __float_as_uint(v));
    }
    asm volatile("s_waitcnt vmcnt(0)" ::: "memory");
    if (lane == 0) ATOM_ST(&ws->flagTop[wg][nh], 0);
  } else {
    if (lane < 32) {
      const int c = nh*32 + lane;
      float v = bf2f(sh[32*PR + c]) + bf2f(sl[32*PR + c]);
      ATOM_ST(&ws->haloBot[wg][0][c], __float_as_uint(v));
    }
    asm volatile("s_waitcnt vmcnt(0)" ::: "memory");
    if (lane == 0) ATOM_ST(&ws->flagBot[wg][nh], 0);
  }

  // ---- scan over columns ----
  for (int w = 1; w < W512; ++w) {
    float cv[8];
#pragma unroll
    for (int j = 0; j < 8; ++j) cv[j] = featT[(size_t)j*HWp + w];

    const int slotR = (w - 1) & 1;
    if (wid == 1 && kband > 0) {
      int f0 = -1, f1 = -1;
      while (f0 < w-1 || f1 < w-1) {
        if (lane == 0) {
          f0 = ATOM_LD(&ws->flagBot[wg-1][0]);
          f1 = ATOM_LD(&ws->flagBot[wg-1][1]);
        }
        f0 = __shfl(f0, 0); f1 = __shfl(f1, 0);
        if (f0 < w-1 || f1 < w-1) __builtin_amdgcn_s_sleep(1);
      }
      asm volatile("" ::: "memory");   // no hoisting of halo load above the spin
      float v = __uint_as_float(ATOM_LD(&ws->haloBot[wg-1][slotR][lane]));
      u16 h_ = f2bf(v);
      sh[0*PR + lane] = h_;
      sl[0*PR + lane] = f2bf(v - bf2f(h_));
    }
    if (wid == 2 && kband < 15) {
      int f0 = -1, f1 = -1;
      while (f0 < w-1 || f1 < w-1) {
        if (lane == 0) {
          f0 = ATOM_LD(&ws->flagTop[wg+1][0]);
          f1 = ATOM_LD(&ws->flagTop[wg+1][1]);
        }
        f0 = __shfl(f0, 0); f1 = __shfl(f1, 0);
        if (f0 < w-1 || f1 < w-1) __builtin_amdgcn_s_sleep(1);
      }
      asm volatile("" ::: "memory");
      float v = __uint_as_float(ATOM_LD(&ws->haloTop[wg+1][slotR][lane]));
      u16 h_ = f2bf(v);
      sh[33*PR + lane] = h_;
      sl[33*PR + lane] = f2bf(v - bf2f(h_));
    }

    // store current column to LDS (f32 + hi/lo bf16)
#pragma unroll
    for (int j = 0; j < 8; ++j) {
      s_curf[hh*68 + cb + j] = cv[j];
      u16 h_ = f2bf(cv[j]);
      uh[hh*PR + cb + j] = h_;
      ul[hh*PR + cb + j] = f2bf(cv[j] - bf2f(h_));
    }
    __syncthreads();

    // ---- MFMA: acc[0]=r, acc[1]=z, acc[2]=i_n (x-path), acc[3]=h_n ----
    f32x4 acc[4][2];
#pragma unroll
    for (int p = 0; p < 2; ++p) {
      acc[0][p] = splat4(biasR[p]);
      acc[1][p] = splat4(biasZ[p]);
      acc[2][p] = splat4(biasI[p]);
      acc[3][p] = splat4(biasHn[p]);
    }
#pragma unroll
    for (int kk = 0; kk < 6; ++kk) {
      const int ro = (rt*16 + ln16 + (kk>>1))*PR + (kk&1)*32 + kgrp*8;
      short8 Ah = *(const short8*)&sh[ro];
      short8 Al = *(const short8*)&sl[ro];
#pragma unroll
      for (int g = 0; g < 3; ++g)
#pragma unroll
        for (int p = 0; p < 2; ++p) {
          short8 Bl = *(const short8*)&loIH[(size_t)(((g*4 + nh*2 + p)*6 + kk)*64 + lane)*8];
          f32x4 a = acc[g][p];
          a = MFMA16(Ah, Bih[g][p][kk], a);
          a = MFMA16(Al, Bih[g][p][kk], a);
          a = MFMA16(Ah, Bl, a);
          a = MFMA16(Al, Bl, a);
          acc[g][p] = a;
        }
    }
#pragma unroll
    for (int kt = 0; kt < 2; ++kt) {
      const int ro = (rt*16 + ln16)*PR + kt*32 + kgrp*8;
      short8 Ah = *(const short8*)&uh[ro];
      short8 Al = *(const short8*)&ul[ro];
#pragma unroll
      for (int g = 0; g < 3; ++g)
#pragma unroll
        for (int p = 0; p < 2; ++p) {
          short8 Bl = *(const short8*)&loHH[(size_t)(((g*4 + nh*2 + p)*2 + kt)*64 + lane)*8];
          const int gd = (g == 2) ? 3 : g;
          f32x4 a = acc[gd][p];
          a = MFMA16(Ah, Bhh[g][p][kt], a);
          a = MFMA16(Al, Bhh[g][p][kt], a);
          a = MFMA16(Ah, Bl, a);
          a = MFMA16(Al, Bl, a);
          acc[gd][p] = a;
        }
    }

    // ---- gates + output + halos + state writeback ----
    float hn[2][4];
#pragma unroll
    for (int p = 0; p < 2; ++p)
#pragma unroll
      for (int j = 0; j < 4; ++j) {
        float r = sigm(acc[0][p][j]);
        float z = sigm(acc[1][p][j]);
        float n = tanh_(acc[2][p][j] + r * acc[3][p][j]);
        float cur = s_curf[(rt*16 + kgrp*4 + j)*68 + nh*32 + p*16 + ln16];
        hn[p][j] = (1.f - z)*n + z*cur;
      }
    {
      float* o = out + (size_t)(b*C64 + nh*32 + ln16)*HWp
                     + (size_t)(h0 + rt*16 + kgrp*4)*W512 + w;
#pragma unroll
      for (int p = 0; p < 2; ++p)
#pragma unroll
        for (int j = 0; j < 4; ++j)
          o[(size_t)(p*16)*HWp + j*W512] = hn[p][j];
    }
    const int slotW = w & 1;
    if (rt == 0) {            // band row 0 lives in kgrp 0, reg 0
      if (kgrp == 0) {
#pragma unroll
        for (int p = 0; p < 2; ++p)
          ATOM_ST(&ws->haloTop[wg][slotW][nh*32 + p*16 + ln16], __float_as_uint(hn[p][0]));
      }
      asm volatile("s_waitcnt vmcnt(0)" ::: "memory");
      if (lane == 0) ATOM_ST(&ws->flagTop[wg][nh], w);
    } else {                  // band row 31 lives in kgrp 3, reg 3
      if (kgrp == 3) {
#pragma unroll
        for (int p = 0; p < 2; ++p)
          ATOM_ST(&ws->haloBot[wg][slotW][nh*32 + p*16 + ln16], __float_as_uint(hn[p][3]));
      }
      asm volatile("s_waitcnt vmcnt(0)" ::: "memory");
      if (lane == 0) ATOM_ST(&ws->flagBot[wg][nh], w);
    }

    __syncthreads();   // all reads of old state/cur complete

#pragma unroll
    for (int p = 0; p < 2; ++p)
#pragma unroll
      for (int j = 0; j < 4; ++j) {
        float v = hn[p][j];
        u16 h_ = f2bf(v);
        const int r = 1 + rt*16 + kgrp*4 + j;
        const int c = nh*32 + p*16 + ln16;
        sh[r*PR + c] = h_;
        sl[r*PR + c] = f2bf(v - bf2f(h_));
      }
  }
}

extern "C" void kernel_launch(void* const* d_in, const int* in_sizes, int n_in,
                              void* d_out, int out_size, void* d_ws, size_t ws_size,
                              hipStream_t stream) {
  const float* feat = (const float*)d_in[0];
  const float* wih  = (const float*)d_in[1];
  const float* whh  = (const float*)d_in[2];
  const float* bih  = (const float*)d_in[3];
  const float* bhh  = (const float*)d_in[4];
  float* out = (float*)d_out;
  Ws* ws = (Ws*)d_ws;
  u16* loIH = (u16*)((char*)d_ws + LOIH_OFF);
  u16* loHH = (u16*)((char*)d_ws + LOHH_OFF);

  reset_flags<<<1, 256, 0, stream>>>((int*)d_ws);
  prep_lofrags<<<(LOIH_ENT + LOHH_ENT + 255)/256, 256, 0, stream>>>(wih, whh, loIH, loHH);
  gru_scan<<<NWG, 256, 0, stream>>>(feat, wih, whh, bih, bhh, out, ws, loIH, loHH);
}

// Round 5
// 3996.290 us; speedup vs baseline: 2.1382x; 2.1382x over previous
//
#include <hip/hip_runtime.h>

typedef short short8 __attribute__((ext_vector_type(8)));
typedef float f32x4 __attribute__((ext_vector_type(4)));
typedef unsigned short u16;
typedef unsigned int u32;

#define C64 64
#define HWp (512*512)
#define NWG 64
#define PR 72      // LDS row stride in u16 (144 B, 16B-aligned)
#define NROW 48    // rows computed per step (3 MFMA M-tiles)
#define T7 7       // columns per epoch (511 = 7*73)
#define NEP 73

struct Ws {
  int flags[NWG];            // epoch counter per band (-1 = not posted)
  int _pad[64];
  u32 haloT[NWG][2][8*64];   // band's rows m=7..14  (absrows a..a+7), f32 bits
  u32 haloB[NWG][2][7*64];   // band's rows m=32..38 (absrows a+25..a+31), f32 bits
};

__device__ __forceinline__ u16 f2bf(float f){
  u32 u = __float_as_uint(f);
  u += 0x7fffu + ((u >> 16) & 1u);
  return (u16)(u >> 16);
}
__device__ __forceinline__ float bf2f(u16 h){ return __uint_as_float(((u32)h) << 16); }
__device__ __forceinline__ f32x4 splat4(float x){ f32x4 v = {x,x,x,x}; return v; }
__device__ __forceinline__ float sigm(float x){ return 1.f/(1.f + __expf(-x)); }
__device__ __forceinline__ float tanh_(float x){ float e = __expf(2.f*x); return 1.f - 2.f/(e + 1.f); }

#define MFMA16(a,b,c) __builtin_amdgcn_mfma_f32_16x16x32_bf16(a,b,c,0,0,0)
#define ATOM_ST(p,v) __hip_atomic_store((p),(v),__ATOMIC_RELAXED,__HIP_MEMORY_SCOPE_AGENT)
#define ATOM_LD(p)   __hip_atomic_load((p),__ATOMIC_RELAXED,__HIP_MEMORY_SCOPE_AGENT)
// 4-term hi/lo product: exact to ~2^-16 relative
#define DOT4(acc, XH, XL, WH, WL) \
  acc = MFMA16(XH, WH, acc); acc = MFMA16(XL, WH, acc); \
  acc = MFMA16(XH, WL, acc); acc = MFMA16(XL, WL, acc);

__global__ void reset_flags(int* flags) {
  if (threadIdx.x < NWG) flags[threadIdx.x] = -1;
}

__global__ __launch_bounds__(256, 1)
void gru_scan(const float* __restrict__ feat,
              const float* __restrict__ w_ih,
              const float* __restrict__ w_hh,
              const float* __restrict__ b_ih,
              const float* __restrict__ b_hh,
              float* __restrict__ out,
              Ws* __restrict__ ws)
{
  // state slots 0..49: slot s = absrow (a-8+s), hi/lo bf16 planes
  __shared__ __align__(16) u16 sh[50*PR], sl[50*PR];
  // current feat column, rows m=0..47 (absrow a-7+m), hi/lo bf16
  __shared__ __align__(16) u16 uh[NROW*PR], ul[NROW*PR];
  // output stage: [row 0..31][col 0..6][ch 0..63] bf16
  __shared__ u16 ostage[32*T7*64];

  const int tid  = threadIdx.x;
  const int wg   = blockIdx.x;
  const int b    = wg >> 4;
  const int kband= wg & 15;
  const int a    = kband * 32;          // first owned row
  const int lane = tid & 63;
  const int wid  = tid >> 6;            // 0..3 = ch-quarter
  const int ln16 = lane & 15;
  const int kgrp = lane >> 4;
  const int ch   = wid*16 + ln16;       // global channel this thread outputs

  // ---- weights (hi+lo) fully in registers ----
  short8 BihH[3][6], BihL[3][6], BhhH[3][2], BhhL[3][2];
#pragma unroll
  for (int g = 0; g < 3; ++g) {
    const int n = g*64 + ch;
#pragma unroll
    for (int kk = 0; kk < 6; ++kk) {
      short8 vh, vl;
#pragma unroll
      for (int j = 0; j < 8; ++j) {
        float wv = w_ih[n*192 + kk*32 + kgrp*8 + j];
        u16 h = f2bf(wv); vh[j] = (short)h; vl[j] = (short)f2bf(wv - bf2f(h));
      }
      BihH[g][kk] = vh; BihL[g][kk] = vl;
    }
#pragma unroll
    for (int kt = 0; kt < 2; ++kt) {
      short8 vh, vl;
#pragma unroll
      for (int j = 0; j < 8; ++j) {
        float wv = w_hh[n*64 + kt*32 + kgrp*8 + j];
        u16 h = f2bf(wv); vh[j] = (short)h; vl[j] = (short)f2bf(wv - bf2f(h));
      }
      BhhH[g][kt] = vh; BhhL[g][kt] = vl;
    }
  }
  const float biasR  = b_ih[ch]       + b_hh[ch];
  const float biasZ  = b_ih[64 + ch]  + b_hh[64 + ch];
  const float biasI  = b_ih[128 + ch];
  const float biasHn = b_hh[128 + ch];

  // ---- loader mapping: thread loads 12 rows of one channel ----
  const int lch = tid & 63;
  const int lr0 = (tid >> 6) * 12;
  const float* fbase = feat + (size_t)(b*C64 + lch)*HWp;

  // ---- init ----
  for (int i = tid; i < 50*PR; i += 256) { sh[i] = 0; sl[i] = 0; }
  __syncthreads();
  // column 0 -> state + out passthrough; column 1 -> uh/ul
#pragma unroll
  for (int i = 0; i < 12; ++i) {
    const int m = lr0 + i, absr = a - 7 + m;
    if ((unsigned)absr < 512u) {
      float v = fbase[(size_t)absr*512];
      u16 h_ = f2bf(v);
      sh[(m+1)*PR + lch] = h_;
      sl[(m+1)*PR + lch] = f2bf(v - bf2f(h_));
      if (m >= 7 && m < 39) out[(size_t)(b*C64 + lch)*HWp + (size_t)absr*512] = v;
      float v1 = fbase[(size_t)absr*512 + 1];
      u16 h1 = f2bf(v1);
      uh[m*PR + lch] = h1;
      ul[m*PR + lch] = f2bf(v1 - bf2f(h1));
    } else {
      uh[m*PR + lch] = 0; ul[m*PR + lch] = 0;
    }
  }
  __syncthreads();

  // ---- epoch loop ----
  for (int e = 0; e < NEP; ++e) {
    const int par = e & 1;
#pragma unroll 1
    for (int d = 0; d < T7; ++d) {
      const int w = e*T7 + 1 + d;
      // prefetch feat column w+1 (consumed in writeback phase)
      float cv[12];
      {
        const int wn = (w < 511) ? w + 1 : 511;
#pragma unroll
        for (int i = 0; i < 12; ++i) {
          const int absr = a - 7 + lr0 + i;
          cv[i] = ((unsigned)absr < 512u) ? fbase[(size_t)absr*512 + wn] : 0.f;
        }
      }
      // ---- MFMA: 3 M-tiles x {r,z,i | r,z,h} ----
      float hnv[3][4];
#pragma unroll
      for (int t = 0; t < 3; ++t) {
        f32x4 aR = splat4(biasR), aZ = splat4(biasZ);
        f32x4 aI = splat4(biasI), aH = splat4(biasHn);
        short8 Ah[6], Al[6], Xh[2], Xl[2];
#pragma unroll
        for (int kk = 0; kk < 6; ++kk) {
          const int ro = (t*16 + ln16 + (kk>>1))*PR + (kk&1)*32 + kgrp*8;
          Ah[kk] = *(const short8*)&sh[ro];
          Al[kk] = *(const short8*)&sl[ro];
        }
#pragma unroll
        for (int kt = 0; kt < 2; ++kt) {
          const int ro = (t*16 + ln16)*PR + kt*32 + kgrp*8;
          Xh[kt] = *(const short8*)&uh[ro];
          Xl[kt] = *(const short8*)&ul[ro];
        }
#pragma unroll
        for (int kk = 0; kk < 6; ++kk) {
          DOT4(aR, Ah[kk], Al[kk], BihH[0][kk], BihL[0][kk]);
          DOT4(aZ, Ah[kk], Al[kk], BihH[1][kk], BihL[1][kk]);
          DOT4(aI, Ah[kk], Al[kk], BihH[2][kk], BihL[2][kk]);
        }
#pragma unroll
        for (int kt = 0; kt < 2; ++kt) {
          DOT4(aR, Xh[kt], Xl[kt], BhhH[0][kt], BhhL[0][kt]);
          DOT4(aZ, Xh[kt], Xl[kt], BhhH[1][kt], BhhL[1][kt]);
          DOT4(aH, Xh[kt], Xl[kt], BhhH[2][kt], BhhL[2][kt]);
        }
        // gates (cur reconstructed exactly-enough from hi+lo planes)
#pragma unroll
        for (int j = 0; j < 4; ++j) {
          const int m = t*16 + kgrp*4 + j;
          float r = sigm(aR[j]);
          float z = sigm(aZ[j]);
          float n = tanh_(aI[j] + r * aH[j]);
          float cur = bf2f(uh[m*PR + ch]) + bf2f(ul[m*PR + ch]);
          hnv[t][j] = (1.f - z)*n + z*cur;
        }
      }
      __syncthreads();   // B2: all reads of sh/sl/uh/ul done

      // ---- writeback phase ----
#pragma unroll
      for (int t = 0; t < 3; ++t)
#pragma unroll
        for (int j = 0; j < 4; ++j) {
          const int m = t*16 + kgrp*4 + j;
          const int absr = a - 7 + m;
          const float v = hnv[t][j];
          if ((unsigned)absr < 512u) {
            u16 h_ = f2bf(v);
            sh[(m+1)*PR + ch] = h_;
            sl[(m+1)*PR + ch] = f2bf(v - bf2f(h_));
          }
          if (m >= 7 && m < 39)
            ostage[((m-7)*T7 + d)*64 + ch] = f2bf(v);
          if (d == T7-1 && e < NEP-1) {   // epoch-boundary halo send (exact f32)
            if (m >= 7 && m <= 14)
              ATOM_ST(&ws->haloT[wg][par][(m-7)*64 + ch], __float_as_uint(v));
            if (m >= 32 && m <= 38)
              ATOM_ST(&ws->haloB[wg][par][(m-32)*64 + ch], __float_as_uint(v));
          }
        }
      // uh/ul <- column w+1
#pragma unroll
      for (int i = 0; i < 12; ++i) {
        const int m = lr0 + i;
        u16 h_ = f2bf(cv[i]);
        uh[m*PR + lch] = h_;
        ul[m*PR + lch] = f2bf(cv[i] - bf2f(h_));
      }
      if (d < T7-1) __syncthreads();   // B1 of next step
    }

    // ---- epoch boundary ----
    asm volatile("s_waitcnt vmcnt(0)" ::: "memory");  // every wave drains its halo sends
    __syncthreads();                                  // all waves drained + LDS wb done
    if (e < NEP-1 && tid == 0) ATOM_ST(&ws->flags[wg], e);

    if (wid == 0 || wid == 3) {
      // flush epoch's 7 output columns (bf16 stage -> f32 global)
      const int thr = (wid == 0) ? lane : 64 + lane;
#pragma unroll 1
      for (int i = 0; i < 16; ++i) {
        const int ci = thr + 128*i;
        const int c = ci & 63, row = ci >> 6;
        float* go = out + (size_t)(b*C64 + c)*HWp + (size_t)(a + row)*512 + (e*T7 + 1);
#pragma unroll
        for (int dc = 0; dc < T7; ++dc)
          go[dc] = bf2f(ostage[(row*T7 + dc)*64 + c]);
      }
    } else if (e < NEP-1) {
      if (wid == 1 && kband > 0) {          // top halo <- up-neighbor's bottom rows
        int f = -1, guard = 0;
        while (f < e && ++guard < (1<<17)) {
          if (lane == 0) f = ATOM_LD(&ws->flags[wg-1]);
          f = __shfl(f, 0);
          if (f < e) __builtin_amdgcn_s_sleep(1);
        }
        asm volatile("" ::: "memory");
#pragma unroll
        for (int i = 0; i < 7; ++i) {
          // haloB[i] = absrow a-7+i -> slot (a-7+i)-(a-8) = 1+i
          float v = __uint_as_float(ATOM_LD(&ws->haloB[wg-1][par][i*64 + lane]));
          u16 h_ = f2bf(v);
          sh[(1+i)*PR + lane] = h_;
          sl[(1+i)*PR + lane] = f2bf(v - bf2f(h_));
        }
      }
      if (wid == 2 && kband < 15) {         // bottom halo <- down-neighbor's top rows
        int f = -1, guard = 0;
        while (f < e && ++guard < (1<<17)) {
          if (lane == 0) f = ATOM_LD(&ws->flags[wg+1]);
          f = __shfl(f, 0);
          if (f < e) __builtin_amdgcn_s_sleep(1);
        }
        asm volatile("" ::: "memory");
#pragma unroll
        for (int i = 0; i < 8; ++i) {
          // haloT[i] = absrow a+32+i -> slot (a+32+i)-(a-8) = 40+i  (was 41+i: BUG)
          float v = __uint_as_float(ATOM_LD(&ws->haloT[wg+1][par][i*64 + lane]));
          u16 h_ = f2bf(v);
          sh[(40+i)*PR + lane] = h_;
          sl[(40+i)*PR + lane] = f2bf(v - bf2f(h_));
        }
      }
    }
    __syncthreads();   // state consistent; flush complete before next ostage writes
  }
}

extern "C" void kernel_launch(void* const* d_in, const int* in_sizes, int n_in,
                              void* d_out, int out_size, void* d_ws, size_t ws_size,
                              hipStream_t stream) {
  const float* feat = (const float*)d_in[0];
  const float* wih  = (const float*)d_in[1];
  const float* whh  = (const float*)d_in[2];
  const float* bih  = (const float*)d_in[3];
  const float* bhh  = (const float*)d_in[4];
  float* out = (float*)d_out;
  Ws* ws = (Ws*)d_ws;

  reset_flags<<<1, 64, 0, stream>>>(ws->flags);
  gru_scan<<<NWG, 256, 0, stream>>>(feat, wih, whh, bih, bhh, out, ws);
}